// Round 3
// baseline (593.039 us; speedup 1.0000x reference)
//
#include <hip/hip_runtime.h>
#include <cstdint>
#include <cstddef>

#define B_   8
#define E_   16
#define CIN_ 64
#define C_   64
#define HW_  4096

typedef __attribute__((ext_vector_type(8))) short short8;
typedef __attribute__((ext_vector_type(4))) float floatx4;

// selu(x) = scale*x (x>0) ; scale*alpha*(exp(x)-1) (x<=0)
__device__ __forceinline__ float selu_f(float v) {
    const float kAlphaScale = 1.7580993408473766f;  // alpha*scale
    const float kScale      = 1.0507009873554805f;
    return v > 0.0f ? kScale * v : kAlphaScale * (__expf(v) - 1.0f);
}

__device__ __forceinline__ unsigned short f2bf(float f) {
    unsigned int u = __float_as_uint(f);
    u += 0x7fffu + ((u >> 16) & 1u);   // RNE
    return (unsigned short)(u >> 16);
}
__device__ __forceinline__ float bf2f(unsigned short h) {
    return __uint_as_float(((unsigned int)h) << 16);
}

// ---------- W staging, XOR-swizzled [64][64] bf16 (no pad; k ^= (row&7)<<3) ----------
__device__ __forceinline__ void stage_w_sw(const float* __restrict__ W,
                                           unsigned short* Wh, unsigned short* Wl, int t) {
    for (int idx = t; idx < 4096; idx += 256) {
        const int c = idx >> 6, k = idx & 63;
        const int o = c * 64 + (k ^ ((c & 7) << 3));
        const float f = W[idx];
        const unsigned short h = f2bf(f);
        Wh[o] = h;
        Wl[o] = f2bf(f - bf2f(h));
    }
}
__device__ __forceinline__ void stage_w_hi(const float* __restrict__ W,
                                           unsigned short* Wh, int t) {
    for (int idx = t; idx < 4096; idx += 256) {
        const int c = idx >> 6, k = idx & 63;
        Wh[c * 64 + (k ^ ((c & 7) << 3))] = f2bf(W[idx]);
    }
}

// legacy padded staging (fallback out_kernel only)
#define WPAD 72
__device__ __forceinline__ void stage_w(const float* __restrict__ W,
                                        unsigned short* Wh, unsigned short* Wl, int t) {
    for (int idx = t; idx < 4096; idx += 256) {
        const int c = idx >> 6, k = idx & 63;
        const float f = W[idx];
        const unsigned short h = f2bf(f);
        Wh[c * WPAD + k] = h;
        Wl[c * WPAD + k] = f2bf(f - bf2f(h));
    }
}

// ---------------- kernel 1: K/Q conv (MFMA) + gram partials + fused V conv ----------------
// (unchanged from the 211 us measured version)
#define K1_CH 4
#define KCS 18    // sK c-stride (16 px padded to 18)
#define KIS 292   // sK member-stride (16*18+4)

__global__ __launch_bounds__(256, 2)
void dots_kernel(const float* __restrict__ x,
                 const float* __restrict__ Wk, const float* __restrict__ bk,
                 const float* __restrict__ Wq, const float* __restrict__ bq,
                 const float* __restrict__ Wv, const float* __restrict__ bv,
                 unsigned short* __restrict__ vbuf,   // may be null (no V fusion)
                 float* __restrict__ wts, float* __restrict__ part,
                 int use_atomic)
{
    __shared__ float sK[E_ * KIS];
    __shared__ float sQ[E_ * KIS];
    __shared__ __align__(16) unsigned short Wkh[4096], Wkl[4096];
    __shared__ __align__(16) unsigned short Wqh[4096], Wql[4096];
    __shared__ __align__(16) unsigned short Wvh[4096];

    const int t    = threadIdx.x;
    const int b    = blockIdx.x >> 6;
    const int blk  = blockIdx.x & 63;
    const int wv   = t >> 6;          // wave id: members 4wv..4wv+3
    const int lane = t & 63;
    const int quad = lane >> 4;
    const int pxl  = lane & 15;       // B-frag n / D col
    const int m16  = lane & 15;       // A-frag m
    // gram mapping (block-wide)
    const int gc = t >> 4;            // channel-in-quarter
    const int s  = t & 15;
    const int ib = (s >> 2) << 2;
    const int jb = (s & 3) << 2;

    stage_w_sw(Wk, Wkh, Wkl, t);
    stage_w_sw(Wq, Wqh, Wql, t);
    if (vbuf) stage_w_hi(Wv, Wvh, t);

    float acc[4][4][4];
    #pragma unroll
    for (int a0 = 0; a0 < 4; ++a0)
      #pragma unroll
      for (int a1 = 0; a1 < 4; ++a1)
        #pragma unroll
        for (int a2 = 0; a2 < 4; ++a2) acc[a0][a1][a2] = 0.0f;

    __syncthreads();   // W staged

    for (int chunk = 0; chunk < K1_CH; ++chunk) {
        const int p0 = blk * (16 * K1_CH) + chunk * 16;
        const size_t tb = ((size_t)((b * 64 + blk) * 4 + chunk)) * 16384;  // V tile base

        // x B-frags: lane holds x[cin=kk*32+quad*8+j][px=p0+pxl], hi/lo bf16
        short8 xh[4][2], xl[4][2];
        #pragma unroll
        for (int mi = 0; mi < 4; ++mi) {
            const int im = 4 * wv + mi;
            const float* xg = x + ((size_t)(b * E_ + im) * CIN_) * HW_ + p0 + pxl;
            #pragma unroll
            for (int kk = 0; kk < 2; ++kk) {
                float xv[8];
                #pragma unroll
                for (int j = 0; j < 8; ++j)
                    xv[j] = xg[(size_t)(kk * 32 + quad * 8 + j) * HW_];
                #pragma unroll
                for (int j = 0; j < 8; ++j) {
                    const unsigned short h = f2bf(xv[j]);
                    xh[mi][kk][j] = (short)h;
                    xl[mi][kk][j] = (short)f2bf(xv[j] - bf2f(h));
                }
            }
        }

        for (int q4 = 0; q4 < 4; ++q4) {
            const int row = q4 * 16 + m16;
            const int ksw = (row & 7) << 3;

            // ---- V conv first (global stores issue early, hidden under K/Q conv) ----
            if (vbuf) {
                short8 vh[2];
                #pragma unroll
                for (int kk = 0; kk < 2; ++kk) {
                    const int k0 = kk * 32 + quad * 8;
                    vh[kk] = *(const short8*)&Wvh[row * 64 + (k0 ^ ksw)];
                }
                float bvv[4];
                #pragma unroll
                for (int r = 0; r < 4; ++r) bvv[r] = bv[q4 * 16 + quad * 4 + r];
                #pragma unroll
                for (int mi = 0; mi < 4; ++mi) {
                    floatx4 d = {0.f, 0.f, 0.f, 0.f};
                    d = __builtin_amdgcn_mfma_f32_16x16x32_bf16(vh[0], xh[mi][0], d, 0, 0, 0);
                    d = __builtin_amdgcn_mfma_f32_16x16x32_bf16(vh[0], xl[mi][0], d, 0, 0, 0);
                    d = __builtin_amdgcn_mfma_f32_16x16x32_bf16(vh[1], xh[mi][1], d, 0, 0, 0);
                    d = __builtin_amdgcn_mfma_f32_16x16x32_bf16(vh[1], xl[mi][1], d, 0, 0, 0);
                    const int im = 4 * wv + mi;
                    #pragma unroll
                    for (int r = 0; r < 4; ++r)
                        vbuf[tb + im * 1024 + (q4 * 16 + quad * 4 + r) * 16 + pxl]
                            = f2bf(d[r] + bvv[r]);
                }
            }

            // ---- K conv for this channel quarter ----
            {
                short8 ah[2], al[2];
                #pragma unroll
                for (int kk = 0; kk < 2; ++kk) {
                    const int k0 = kk * 32 + quad * 8;
                    const int off = row * 64 + (k0 ^ ksw);
                    ah[kk] = *(const short8*)&Wkh[off];
                    al[kk] = *(const short8*)&Wkl[off];
                }
                float bkv[4];
                #pragma unroll
                for (int r = 0; r < 4; ++r) bkv[r] = bk[q4 * 16 + quad * 4 + r];
                #pragma unroll
                for (int mi = 0; mi < 4; ++mi) {
                    floatx4 d = {0.f, 0.f, 0.f, 0.f};
                    #pragma unroll
                    for (int kk = 0; kk < 2; ++kk) {
                        d = __builtin_amdgcn_mfma_f32_16x16x32_bf16(ah[kk], xh[mi][kk], d, 0, 0, 0);
                        d = __builtin_amdgcn_mfma_f32_16x16x32_bf16(ah[kk], xl[mi][kk], d, 0, 0, 0);
                        d = __builtin_amdgcn_mfma_f32_16x16x32_bf16(al[kk], xh[mi][kk], d, 0, 0, 0);
                    }
                    const int im = 4 * wv + mi;
                    #pragma unroll
                    for (int r = 0; r < 4; ++r)
                        sK[im * KIS + (quad * 4 + r) * KCS + pxl] = selu_f(d[r] + bkv[r]);
                }
            }
            // ---- Q conv for this channel quarter ----
            {
                short8 ah[2], al[2];
                #pragma unroll
                for (int kk = 0; kk < 2; ++kk) {
                    const int k0 = kk * 32 + quad * 8;
                    const int off = row * 64 + (k0 ^ ksw);
                    ah[kk] = *(const short8*)&Wqh[off];
                    al[kk] = *(const short8*)&Wql[off];
                }
                float bqv[4];
                #pragma unroll
                for (int r = 0; r < 4; ++r) bqv[r] = bq[q4 * 16 + quad * 4 + r];
                #pragma unroll
                for (int mi = 0; mi < 4; ++mi) {
                    floatx4 d = {0.f, 0.f, 0.f, 0.f};
                    #pragma unroll
                    for (int kk = 0; kk < 2; ++kk) {
                        d = __builtin_amdgcn_mfma_f32_16x16x32_bf16(ah[kk], xh[mi][kk], d, 0, 0, 0);
                        d = __builtin_amdgcn_mfma_f32_16x16x32_bf16(ah[kk], xl[mi][kk], d, 0, 0, 0);
                        d = __builtin_amdgcn_mfma_f32_16x16x32_bf16(al[kk], xh[mi][kk], d, 0, 0, 0);
                    }
                    const int im = 4 * wv + mi;
                    #pragma unroll
                    for (int r = 0; r < 4; ++r)
                        sQ[im * KIS + (quad * 4 + r) * KCS + pxl] = selu_f(d[r] + bqv[r]);
                }
            }
            __syncthreads();
            // ---- gram: dots[c=q4*16+gc][i=ib+u][j=jb+v] += K_i*Q_j over 16 px ----
            #pragma unroll
            for (int p2 = 0; p2 < 8; ++p2) {
                float2 kv[4], qv[4];
                #pragma unroll
                for (int u = 0; u < 4; ++u)
                    kv[u] = *(const float2*)&sK[(ib + u) * KIS + gc * KCS + 2 * p2];
                #pragma unroll
                for (int v = 0; v < 4; ++v)
                    qv[v] = *(const float2*)&sQ[(jb + v) * KIS + gc * KCS + 2 * p2];
                #pragma unroll
                for (int u = 0; u < 4; ++u)
                    #pragma unroll
                    for (int v = 0; v < 4; ++v)
                        acc[q4][u][v] = __fmaf_rn(kv[u].y, qv[v].y,
                                         __fmaf_rn(kv[u].x, qv[v].x, acc[q4][u][v]));
            }
            __syncthreads();
        }
    }

    if (use_atomic) {
        #pragma unroll
        for (int q4 = 0; q4 < 4; ++q4)
          #pragma unroll
          for (int u = 0; u < 4; ++u)
            #pragma unroll
            for (int v = 0; v < 4; ++v)
              atomicAdd(&wts[(((size_t)b * C_ + (q4 * 16 + gc)) * E_ + (ib + u)) * E_ + (jb + v)],
                        acc[q4][u][v]);
    } else {
        float* pb = part + (size_t)blockIdx.x * (C_ * E_ * E_);
        #pragma unroll
        for (int q4 = 0; q4 < 4; ++q4) {
            __syncthreads();
            #pragma unroll
            for (int u = 0; u < 4; ++u)
              #pragma unroll
              for (int v = 0; v < 4; ++v)
                sK[gc * 256 + (ib + u) * 16 + (jb + v)] = acc[q4][u][v];
            __syncthreads();
            for (int e = t; e < 4096; e += 256)
                pb[q4 * 4096 + e] = sK[e];
        }
    }
}

// ---------------- kernel 2a: reduce partials ----------------
__global__ __launch_bounds__(256)
void reduce_kernel(const float* __restrict__ part, float* __restrict__ wts)
{
    const int tid = blockIdx.x * 256 + threadIdx.x;  // 0..32767 float4 slots
    const int b   = tid >> 12;
    const int off = tid & 4095;
    float4 sum = make_float4(0.f, 0.f, 0.f, 0.f);
    const float* base = part + (size_t)b * 64 * 16384;
    #pragma unroll 8
    for (int blk = 0; blk < 64; ++blk) {
        float4 v = *(const float4*)(base + (size_t)blk * 16384 + off * 4);
        sum.x += v.x; sum.y += v.y; sum.z += v.z; sum.w += v.w;
    }
    *(float4*)(wts + (size_t)b * 16384 + off * 4) = sum;
}

// ---------------- kernel 2b: softmax over i ----------------
__global__ __launch_bounds__(256)
void softmax_kernel(float* __restrict__ wts)
{
    const int tid = blockIdx.x * 256 + threadIdx.x;  // 8192 = B*C*E(j)
    const int j   = tid & 15;
    const int bc  = tid >> 4;
    float* base = wts + (size_t)bc * 256 + j;
    float v[16];
    #pragma unroll
    for (int i = 0; i < 16; ++i) v[i] = base[i * 16];
    float m = v[0];
    #pragma unroll
    for (int i = 1; i < 16; ++i) m = fmaxf(m, v[i]);
    float sum = 0.f;
    #pragma unroll
    for (int i = 0; i < 16; ++i) { v[i] = __expf(v[i] - m); sum += v[i]; }
    const float r = 1.0f / sum;
    #pragma unroll
    for (int i = 0; i < 16; ++i) base[i * 16] = v[i] * r;
}

// ---------------- kernel 3 (fused path): no-LDS wave-per-(b,tile,c) combine ----------------
// grid 8192 = B(8) x tile(64) x cgroup(16); block 256 = 4 waves, wave wv owns c = cg*4+wv.
// Lane layout: ih = lane>>5 selects even/odd members; lx = lane&31 -> px pair 2*lx.
// Each lane accumulates 8 members into acc[16 j][2 px]; one shfl_xor(32) butterfly
// completes the 16-member sum; lanes<32 store j 0-7 rows, lanes>=32 store j 8-15.
// All reads/writes are full-line coalesced; zero LDS, zero barriers.
__global__ __launch_bounds__(256, 4)
void combine_kernel(const unsigned short* __restrict__ vbuf,
                    const float* __restrict__ wts, float* __restrict__ out)
{
    const int t   = threadIdx.x;
    const int wv  = t >> 6;
    const int l   = t & 63;
    const int bid = blockIdx.x;
    const int b   = bid >> 10;            // 8 batches
    const int blk = (bid >> 4) & 63;      // 64-px tile
    const int cg  = bid & 15;             // channel group of 4
    const int c   = cg * 4 + wv;

    const int ih    = l >> 5;             // member parity (0: even i, 1: odd i)
    const int lx    = l & 31;             // px pair index
    const int px    = 2 * lx;
    const int chunk = lx >> 3;            // which 16-px sub-tile
    const int inpx  = px & 15;

    const unsigned short* vb = vbuf + ((size_t)(b * 64 + blk)) * 65536
                             + chunk * 16384 + c * 16 + inpx;
    const float* wb = wts + (((size_t)(b * 64 + c)) * 16) * 16;

    float acc[16][2];
    #pragma unroll
    for (int j = 0; j < 16; ++j) { acc[j][0] = 0.f; acc[j][1] = 0.f; }

    #pragma unroll
    for (int ip = 0; ip < 8; ++ip) {
        const int i = 2 * ip + ih;
        const unsigned int u = *(const unsigned int*)(vb + i * 1024);
        const float f0 = __uint_as_float(u << 16);
        const float f1 = __uint_as_float(u & 0xffff0000u);
        const float4* wp4 = (const float4*)(wb + i * 16);
        const float4 w0 = wp4[0], w1 = wp4[1], w2 = wp4[2], w3 = wp4[3];
        const float wj[16] = { w0.x, w0.y, w0.z, w0.w,  w1.x, w1.y, w1.z, w1.w,
                               w2.x, w2.y, w2.z, w2.w,  w3.x, w3.y, w3.z, w3.w };
        #pragma unroll
        for (int j = 0; j < 16; ++j) {
            acc[j][0] = __fmaf_rn(wj[j], f0, acc[j][0]);
            acc[j][1] = __fmaf_rn(wj[j], f1, acc[j][1]);
        }
    }

    // butterfly: add the complementary member-parity half (lane ^ 32)
    #pragma unroll
    for (int j = 0; j < 16; ++j) {
        acc[j][0] += __shfl_xor(acc[j][0], 32);
        acc[j][1] += __shfl_xor(acc[j][1], 32);
    }

    // lanes<32 write j rows 0..7, lanes>=32 write j rows 8..15 (full 256B segments)
    #pragma unroll
    for (int jj = 0; jj < 8; ++jj) {
        const float a0 = ih ? acc[jj + 8][0] : acc[jj][0];
        const float a1 = ih ? acc[jj + 8][1] : acc[jj][1];
        float2 o;
        o.x = selu_f(a0);
        o.y = selu_f(a1);
        float* op = out + (((size_t)(b * E_ + jj + 8 * ih) * C_ + c) * HW_) + blk * 64 + px;
        *(float2*)op = o;
    }
}

// ---------------- kernel 3 (fallback): V conv (MFMA) + combine + selu ----------------
#define K3_CH 2
#define VCS 20
#define VIS 1284

__global__ __launch_bounds__(256, 2)
void out_kernel(const float* __restrict__ x,
                const float* __restrict__ Wv, const float* __restrict__ bv,
                const float* __restrict__ wts, float* __restrict__ out)
{
    __shared__ __align__(16) unsigned short sV[E_ * VIS];   // V staged bf16
    __shared__ __align__(16) unsigned short Wvh[64 * WPAD], Wvl[64 * WPAD];

    const int t    = threadIdx.x;
    const int b    = blockIdx.x >> 7;
    const int blk  = blockIdx.x & 127;
    const int wv   = t >> 6;
    const int lane = t & 63;
    const int quad = lane >> 4;
    const int pxl  = lane & 15;
    const int m16  = lane & 15;
    const int c    = t >> 2;     // combine: channel
    const int q    = t & 3;      // combine: j-quad

    stage_w(Wv, Wvh, Wvl, t);
    __syncthreads();

    for (int chunk = 0; chunk < K3_CH; ++chunk) {
        const int p0 = blk * (16 * K3_CH) + chunk * 16;

        short8 xh[4][2], xl[4][2];
        #pragma unroll
        for (int mi = 0; mi < 4; ++mi) {
            const int im = 4 * wv + mi;
            const float* xg = x + ((size_t)(b * E_ + im) * CIN_) * HW_ + p0 + pxl;
            #pragma unroll
            for (int kk = 0; kk < 2; ++kk) {
                float xv[8];
                #pragma unroll
                for (int j = 0; j < 8; ++j)
                    xv[j] = xg[(size_t)(kk * 32 + quad * 8 + j) * HW_];
                #pragma unroll
                for (int j = 0; j < 8; ++j) {
                    const unsigned short h = f2bf(xv[j]);
                    xh[mi][kk][j] = (short)h;
                    xl[mi][kk][j] = (short)f2bf(xv[j] - bf2f(h));
                }
            }
        }

        #pragma unroll
        for (int cb = 0; cb < 4; ++cb) {
            short8 ah[2], al[2];
            #pragma unroll
            for (int kk = 0; kk < 2; ++kk) {
                const int off = (cb * 16 + m16) * WPAD + kk * 32 + quad * 8;
                ah[kk] = *(const short8*)&Wvh[off];
                al[kk] = *(const short8*)&Wvl[off];
            }
            float bvv[4];
            #pragma unroll
            for (int r = 0; r < 4; ++r) bvv[r] = bv[cb * 16 + quad * 4 + r];
            #pragma unroll
            for (int mi = 0; mi < 4; ++mi) {
                floatx4 d = {0.f, 0.f, 0.f, 0.f};
                #pragma unroll
                for (int kk = 0; kk < 2; ++kk) {
                    d = __builtin_amdgcn_mfma_f32_16x16x32_bf16(ah[kk], xh[mi][kk], d, 0, 0, 0);
                    d = __builtin_amdgcn_mfma_f32_16x16x32_bf16(ah[kk], xl[mi][kk], d, 0, 0, 0);
                    d = __builtin_amdgcn_mfma_f32_16x16x32_bf16(al[kk], xh[mi][kk], d, 0, 0, 0);
                }
                const int im = 4 * wv + mi;
                #pragma unroll
                for (int r = 0; r < 4; ++r)
                    sV[im * VIS + (cb * 16 + quad * 4 + r) * VCS + pxl] = f2bf(d[r] + bvv[r]);
            }
        }
        __syncthreads();

        float acc2[4][16];
        #pragma unroll
        for (int jj = 0; jj < 4; ++jj)
            #pragma unroll
            for (int pp = 0; pp < 16; ++pp) acc2[jj][pp] = 0.f;

        #pragma unroll 4
        for (int i2 = 0; i2 < 16; ++i2) {
            const float4 w4 = *(const float4*)&wts[(((size_t)b * C_ + c) * E_ + i2) * E_ + 4 * q];
            const unsigned short* vp = &sV[i2 * VIS + c * VCS];
            float vvv[16];
            #pragma unroll
            for (int pq = 0; pq < 4; ++pq) {
                const uint2 u = *(const uint2*)(vp + 4 * pq);
                vvv[4 * pq + 0] = __uint_as_float(u.x << 16);
                vvv[4 * pq + 1] = __uint_as_float(u.x & 0xffff0000u);
                vvv[4 * pq + 2] = __uint_as_float(u.y << 16);
                vvv[4 * pq + 3] = __uint_as_float(u.y & 0xffff0000u);
            }
            const float wj0 = w4.x, wj1 = w4.y, wj2 = w4.z, wj3 = w4.w;
            #pragma unroll
            for (int pp = 0; pp < 16; ++pp) {
                acc2[0][pp] = __fmaf_rn(wj0, vvv[pp], acc2[0][pp]);
                acc2[1][pp] = __fmaf_rn(wj1, vvv[pp], acc2[1][pp]);
                acc2[2][pp] = __fmaf_rn(wj2, vvv[pp], acc2[2][pp]);
                acc2[3][pp] = __fmaf_rn(wj3, vvv[pp], acc2[3][pp]);
            }
        }

        #pragma unroll
        for (int jj = 0; jj < 4; ++jj) {
            const int j = 4 * q + jj;
            float* op = out + ((size_t)((b * E_ + j) * C_ + c)) * HW_ + p0;
            #pragma unroll
            for (int pq = 0; pq < 4; ++pq) {
                float4 o;
                o.x = selu_f(acc2[jj][4 * pq + 0]);
                o.y = selu_f(acc2[jj][4 * pq + 1]);
                o.z = selu_f(acc2[jj][4 * pq + 2]);
                o.w = selu_f(acc2[jj][4 * pq + 3]);
                *(float4*)(op + 4 * pq) = o;
            }
        }
        __syncthreads();
    }
}

extern "C" void kernel_launch(void* const* d_in, const int* in_sizes, int n_in,
                              void* d_out, int out_size, void* d_ws, size_t ws_size,
                              hipStream_t stream)
{
    (void)in_sizes; (void)n_in; (void)out_size;
    const float* x  = (const float*)d_in[0];
    const float* Wv = (const float*)d_in[1];
    const float* bv = (const float*)d_in[2];
    const float* Wk = (const float*)d_in[3];
    const float* bk = (const float*)d_in[4];
    const float* Wq = (const float*)d_in[5];
    const float* bq = (const float*)d_in[6];
    float* out = (float*)d_out;

    const size_t wts_b  = (size_t)B_ * C_ * E_ * E_ * sizeof(float);        // 0.5 MB
    const size_t part_b = (size_t)512 * C_ * E_ * E_ * sizeof(float);       // 33.5 MB
    const size_t v_b    = (size_t)B_ * E_ * C_ * HW_ * sizeof(unsigned short); // 67.1 MB

    float* wts = (float*)d_ws;
    float* part = nullptr;
    unsigned short* vbuf = nullptr;
    int use_atomic, have_v;

    if (ws_size >= wts_b + part_b + v_b) {
        use_atomic = 0; have_v = 1;
        part = (float*)((char*)d_ws + wts_b);
        vbuf = (unsigned short*)((char*)d_ws + wts_b + part_b);
    } else if (ws_size >= wts_b + part_b) {
        use_atomic = 0; have_v = 0;
        part = (float*)((char*)d_ws + wts_b);
    } else if (ws_size >= wts_b + v_b) {
        use_atomic = 1; have_v = 1;
        vbuf = (unsigned short*)((char*)d_ws + wts_b);
    } else {
        use_atomic = 1; have_v = 0;
    }

    if (use_atomic)
        hipMemsetAsync(d_ws, 0, wts_b, stream);

    dots_kernel<<<dim3(512), dim3(256), 0, stream>>>(x, Wk, bk, Wq, bq, Wv, bv,
                                                     vbuf, wts, part, use_atomic);
    if (!use_atomic)
        reduce_kernel<<<dim3(128), dim3(256), 0, stream>>>(part, wts);
    softmax_kernel<<<dim3(32), dim3(256), 0, stream>>>(wts);
    if (have_v)
        combine_kernel<<<dim3(8192), dim3(256), 0, stream>>>(vbuf, wts, out);
    else
        out_kernel<<<dim3(1024), dim3(256), 0, stream>>>(x, Wv, bv, wts, out);
}

// Round 4
// 443.254 us; speedup vs baseline: 1.3379x; 1.3379x over previous
//
#include <hip/hip_runtime.h>
#include <cstdint>
#include <cstddef>

#define B_   8
#define E_   16
#define CIN_ 64
#define C_   64
#define HW_  4096

typedef __attribute__((ext_vector_type(8))) short short8;
typedef __attribute__((ext_vector_type(4))) float floatx4;

// selu(x) = scale*x (x>0) ; scale*alpha*(exp(x)-1) (x<=0)
__device__ __forceinline__ float selu_f(float v) {
    const float kAlphaScale = 1.7580993408473766f;  // alpha*scale
    const float kScale      = 1.0507009873554805f;
    return v > 0.0f ? kScale * v : kAlphaScale * (__expf(v) - 1.0f);
}

__device__ __forceinline__ unsigned short f2bf(float f) {
    unsigned int u = __float_as_uint(f);
    u += 0x7fffu + ((u >> 16) & 1u);   // RNE
    return (unsigned short)(u >> 16);
}
__device__ __forceinline__ float bf2f(unsigned short h) {
    return __uint_as_float(((unsigned int)h) << 16);
}

// ---------- W staging, XOR-swizzled [64][64] bf16 (no pad; k ^= (row&7)<<3) ----------
__device__ __forceinline__ void stage_w_sw(const float* __restrict__ W,
                                           unsigned short* Wh, unsigned short* Wl, int t) {
    for (int idx = t; idx < 4096; idx += 256) {
        const int c = idx >> 6, k = idx & 63;
        const int o = c * 64 + (k ^ ((c & 7) << 3));
        const float f = W[idx];
        const unsigned short h = f2bf(f);
        Wh[o] = h;
        Wl[o] = f2bf(f - bf2f(h));
    }
}
__device__ __forceinline__ void stage_w_hi(const float* __restrict__ W,
                                           unsigned short* Wh, int t) {
    for (int idx = t; idx < 4096; idx += 256) {
        const int c = idx >> 6, k = idx & 63;
        Wh[c * 64 + (k ^ ((c & 7) << 3))] = f2bf(W[idx]);
    }
}

// legacy padded staging (fallback out_kernel only)
#define WPAD 72
__device__ __forceinline__ void stage_w(const float* __restrict__ W,
                                        unsigned short* Wh, unsigned short* Wl, int t) {
    for (int idx = t; idx < 4096; idx += 256) {
        const int c = idx >> 6, k = idx & 63;
        const float f = W[idx];
        const unsigned short h = f2bf(f);
        Wh[c * WPAD + k] = h;
        Wl[c * WPAD + k] = f2bf(f - bf2f(h));
    }
}

// ---------------- kernel 1: K/Q conv (MFMA) + gram partials + fused V conv ----------------
// (unchanged from the 211 us measured version)
#define K1_CH 4
#define KCS 18    // sK c-stride (16 px padded to 18)
#define KIS 292   // sK member-stride (16*18+4)

__global__ __launch_bounds__(256, 2)
void dots_kernel(const float* __restrict__ x,
                 const float* __restrict__ Wk, const float* __restrict__ bk,
                 const float* __restrict__ Wq, const float* __restrict__ bq,
                 const float* __restrict__ Wv, const float* __restrict__ bv,
                 unsigned short* __restrict__ vbuf,   // may be null (no V fusion)
                 float* __restrict__ wts, float* __restrict__ part,
                 int use_atomic)
{
    __shared__ float sK[E_ * KIS];
    __shared__ float sQ[E_ * KIS];
    __shared__ __align__(16) unsigned short Wkh[4096], Wkl[4096];
    __shared__ __align__(16) unsigned short Wqh[4096], Wql[4096];
    __shared__ __align__(16) unsigned short Wvh[4096];

    const int t    = threadIdx.x;
    const int b    = blockIdx.x >> 6;
    const int blk  = blockIdx.x & 63;
    const int wv   = t >> 6;          // wave id: members 4wv..4wv+3
    const int lane = t & 63;
    const int quad = lane >> 4;
    const int pxl  = lane & 15;       // B-frag n / D col
    const int m16  = lane & 15;       // A-frag m
    // gram mapping (block-wide)
    const int gc = t >> 4;            // channel-in-quarter
    const int s  = t & 15;
    const int ib = (s >> 2) << 2;
    const int jb = (s & 3) << 2;

    stage_w_sw(Wk, Wkh, Wkl, t);
    stage_w_sw(Wq, Wqh, Wql, t);
    if (vbuf) stage_w_hi(Wv, Wvh, t);

    float acc[4][4][4];
    #pragma unroll
    for (int a0 = 0; a0 < 4; ++a0)
      #pragma unroll
      for (int a1 = 0; a1 < 4; ++a1)
        #pragma unroll
        for (int a2 = 0; a2 < 4; ++a2) acc[a0][a1][a2] = 0.0f;

    __syncthreads();   // W staged

    for (int chunk = 0; chunk < K1_CH; ++chunk) {
        const int p0 = blk * (16 * K1_CH) + chunk * 16;
        const size_t tb = ((size_t)((b * 64 + blk) * 4 + chunk)) * 16384;  // V tile base

        // x B-frags: lane holds x[cin=kk*32+quad*8+j][px=p0+pxl], hi/lo bf16
        short8 xh[4][2], xl[4][2];
        #pragma unroll
        for (int mi = 0; mi < 4; ++mi) {
            const int im = 4 * wv + mi;
            const float* xg = x + ((size_t)(b * E_ + im) * CIN_) * HW_ + p0 + pxl;
            #pragma unroll
            for (int kk = 0; kk < 2; ++kk) {
                float xv[8];
                #pragma unroll
                for (int j = 0; j < 8; ++j)
                    xv[j] = xg[(size_t)(kk * 32 + quad * 8 + j) * HW_];
                #pragma unroll
                for (int j = 0; j < 8; ++j) {
                    const unsigned short h = f2bf(xv[j]);
                    xh[mi][kk][j] = (short)h;
                    xl[mi][kk][j] = (short)f2bf(xv[j] - bf2f(h));
                }
            }
        }

        for (int q4 = 0; q4 < 4; ++q4) {
            const int row = q4 * 16 + m16;
            const int ksw = (row & 7) << 3;

            // ---- V conv first (global stores issue early, hidden under K/Q conv) ----
            if (vbuf) {
                short8 vh[2];
                #pragma unroll
                for (int kk = 0; kk < 2; ++kk) {
                    const int k0 = kk * 32 + quad * 8;
                    vh[kk] = *(const short8*)&Wvh[row * 64 + (k0 ^ ksw)];
                }
                float bvv[4];
                #pragma unroll
                for (int r = 0; r < 4; ++r) bvv[r] = bv[q4 * 16 + quad * 4 + r];
                #pragma unroll
                for (int mi = 0; mi < 4; ++mi) {
                    floatx4 d = {0.f, 0.f, 0.f, 0.f};
                    d = __builtin_amdgcn_mfma_f32_16x16x32_bf16(vh[0], xh[mi][0], d, 0, 0, 0);
                    d = __builtin_amdgcn_mfma_f32_16x16x32_bf16(vh[0], xl[mi][0], d, 0, 0, 0);
                    d = __builtin_amdgcn_mfma_f32_16x16x32_bf16(vh[1], xh[mi][1], d, 0, 0, 0);
                    d = __builtin_amdgcn_mfma_f32_16x16x32_bf16(vh[1], xl[mi][1], d, 0, 0, 0);
                    const int im = 4 * wv + mi;
                    #pragma unroll
                    for (int r = 0; r < 4; ++r)
                        vbuf[tb + im * 1024 + (q4 * 16 + quad * 4 + r) * 16 + pxl]
                            = f2bf(d[r] + bvv[r]);
                }
            }

            // ---- K conv for this channel quarter ----
            {
                short8 ah[2], al[2];
                #pragma unroll
                for (int kk = 0; kk < 2; ++kk) {
                    const int k0 = kk * 32 + quad * 8;
                    const int off = row * 64 + (k0 ^ ksw);
                    ah[kk] = *(const short8*)&Wkh[off];
                    al[kk] = *(const short8*)&Wkl[off];
                }
                float bkv[4];
                #pragma unroll
                for (int r = 0; r < 4; ++r) bkv[r] = bk[q4 * 16 + quad * 4 + r];
                #pragma unroll
                for (int mi = 0; mi < 4; ++mi) {
                    floatx4 d = {0.f, 0.f, 0.f, 0.f};
                    #pragma unroll
                    for (int kk = 0; kk < 2; ++kk) {
                        d = __builtin_amdgcn_mfma_f32_16x16x32_bf16(ah[kk], xh[mi][kk], d, 0, 0, 0);
                        d = __builtin_amdgcn_mfma_f32_16x16x32_bf16(ah[kk], xl[mi][kk], d, 0, 0, 0);
                        d = __builtin_amdgcn_mfma_f32_16x16x32_bf16(al[kk], xh[mi][kk], d, 0, 0, 0);
                    }
                    const int im = 4 * wv + mi;
                    #pragma unroll
                    for (int r = 0; r < 4; ++r)
                        sK[im * KIS + (quad * 4 + r) * KCS + pxl] = selu_f(d[r] + bkv[r]);
                }
            }
            // ---- Q conv for this channel quarter ----
            {
                short8 ah[2], al[2];
                #pragma unroll
                for (int kk = 0; kk < 2; ++kk) {
                    const int k0 = kk * 32 + quad * 8;
                    const int off = row * 64 + (k0 ^ ksw);
                    ah[kk] = *(const short8*)&Wqh[off];
                    al[kk] = *(const short8*)&Wql[off];
                }
                float bqv[4];
                #pragma unroll
                for (int r = 0; r < 4; ++r) bqv[r] = bq[q4 * 16 + quad * 4 + r];
                #pragma unroll
                for (int mi = 0; mi < 4; ++mi) {
                    floatx4 d = {0.f, 0.f, 0.f, 0.f};
                    #pragma unroll
                    for (int kk = 0; kk < 2; ++kk) {
                        d = __builtin_amdgcn_mfma_f32_16x16x32_bf16(ah[kk], xh[mi][kk], d, 0, 0, 0);
                        d = __builtin_amdgcn_mfma_f32_16x16x32_bf16(ah[kk], xl[mi][kk], d, 0, 0, 0);
                        d = __builtin_amdgcn_mfma_f32_16x16x32_bf16(al[kk], xh[mi][kk], d, 0, 0, 0);
                    }
                    const int im = 4 * wv + mi;
                    #pragma unroll
                    for (int r = 0; r < 4; ++r)
                        sQ[im * KIS + (quad * 4 + r) * KCS + pxl] = selu_f(d[r] + bqv[r]);
                }
            }
            __syncthreads();
            // ---- gram: dots[c=q4*16+gc][i=ib+u][j=jb+v] += K_i*Q_j over 16 px ----
            #pragma unroll
            for (int p2 = 0; p2 < 8; ++p2) {
                float2 kv[4], qv[4];
                #pragma unroll
                for (int u = 0; u < 4; ++u)
                    kv[u] = *(const float2*)&sK[(ib + u) * KIS + gc * KCS + 2 * p2];
                #pragma unroll
                for (int v = 0; v < 4; ++v)
                    qv[v] = *(const float2*)&sQ[(jb + v) * KIS + gc * KCS + 2 * p2];
                #pragma unroll
                for (int u = 0; u < 4; ++u)
                    #pragma unroll
                    for (int v = 0; v < 4; ++v)
                        acc[q4][u][v] = __fmaf_rn(kv[u].y, qv[v].y,
                                         __fmaf_rn(kv[u].x, qv[v].x, acc[q4][u][v]));
            }
            __syncthreads();
        }
    }

    if (use_atomic) {
        #pragma unroll
        for (int q4 = 0; q4 < 4; ++q4)
          #pragma unroll
          for (int u = 0; u < 4; ++u)
            #pragma unroll
            for (int v = 0; v < 4; ++v)
              atomicAdd(&wts[(((size_t)b * C_ + (q4 * 16 + gc)) * E_ + (ib + u)) * E_ + (jb + v)],
                        acc[q4][u][v]);
    } else {
        float* pb = part + (size_t)blockIdx.x * (C_ * E_ * E_);
        #pragma unroll
        for (int q4 = 0; q4 < 4; ++q4) {
            __syncthreads();
            #pragma unroll
            for (int u = 0; u < 4; ++u)
              #pragma unroll
              for (int v = 0; v < 4; ++v)
                sK[gc * 256 + (ib + u) * 16 + (jb + v)] = acc[q4][u][v];
            __syncthreads();
            for (int e = t; e < 4096; e += 256)
                pb[q4 * 4096 + e] = sK[e];
        }
    }
}

// ---------------- kernel 2a: reduce partials ----------------
__global__ __launch_bounds__(256)
void reduce_kernel(const float* __restrict__ part, float* __restrict__ wts)
{
    const int tid = blockIdx.x * 256 + threadIdx.x;  // 0..32767 float4 slots
    const int b   = tid >> 12;
    const int off = tid & 4095;
    float4 sum = make_float4(0.f, 0.f, 0.f, 0.f);
    const float* base = part + (size_t)b * 64 * 16384;
    #pragma unroll 8
    for (int blk = 0; blk < 64; ++blk) {
        float4 v = *(const float4*)(base + (size_t)blk * 16384 + off * 4);
        sum.x += v.x; sum.y += v.y; sum.z += v.z; sum.w += v.w;
    }
    *(float4*)(wts + (size_t)b * 16384 + off * 4) = sum;
}

// ---------------- kernel 2b: softmax over i ----------------
__global__ __launch_bounds__(256)
void softmax_kernel(float* __restrict__ wts)
{
    const int tid = blockIdx.x * 256 + threadIdx.x;  // 8192 = B*C*E(j)
    const int j   = tid & 15;
    const int bc  = tid >> 4;
    float* base = wts + (size_t)bc * 256 + j;
    float v[16];
    #pragma unroll
    for (int i = 0; i < 16; ++i) v[i] = base[i * 16];
    float m = v[0];
    #pragma unroll
    for (int i = 1; i < 16; ++i) m = fmaxf(m, v[i]);
    float sum = 0.f;
    #pragma unroll
    for (int i = 0; i < 16; ++i) { v[i] = __expf(v[i] - m); sum += v[i]; }
    const float r = 1.0f / sum;
    #pragma unroll
    for (int i = 0; i < 16; ++i) base[i * 16] = v[i] * r;
}

// ---------------- kernel 3 (fused path): no-LDS, no-shuffle combine ----------------
// grid 8192 = B(8) x tile(64) x cgroup(16); block 256 = 4 waves; wave wv owns c = cg*4+wv.
// Lanes 0-31 produce j rows 0-7, lanes 32-63 rows 8-15; lane lx owns px pair 2*lx.
// Each lane loops over ALL 16 members: lanes lx and lx+32 read the same V word
// (merged request), so HBM fetch stays 1x. Accumulator = 8 named float2 (16 VGPR);
// weights load as two named float4 per member, consumed immediately. No local
// arrays -> nothing for the compiler to demote to scratch (R3 lesson: VGPR=32 +
// 557MB WRITE was acc/wj spill traffic).
__global__ __launch_bounds__(256)
void combine_kernel(const unsigned short* __restrict__ vbuf,
                    const float* __restrict__ wts, float* __restrict__ out)
{
    const int t   = threadIdx.x;
    const int wv  = t >> 6;
    const int l   = t & 63;
    const int bid = blockIdx.x;
    const int b   = bid >> 10;            // 8 batches
    const int blk = (bid >> 4) & 63;      // 64-px tile
    const int cg  = bid & 15;             // channel group of 4
    const int c   = cg * 4 + wv;

    const int ih    = l >> 5;             // j half: rows 8*ih .. 8*ih+7
    const int lx    = l & 31;             // px pair index
    const int px    = 2 * lx;
    const int chunk = lx >> 3;            // which 16-px sub-tile
    const int inpx  = px & 15;

    const unsigned short* vb = vbuf + ((size_t)(b * 64 + blk)) * 65536
                             + chunk * 16384 + c * 16 + inpx;
    const float* wb = wts + ((size_t)(b * 64 + c)) * 256 + 8 * ih;

    float2 a0 = {0.f, 0.f}, a1 = {0.f, 0.f}, a2 = {0.f, 0.f}, a3 = {0.f, 0.f};
    float2 a4 = {0.f, 0.f}, a5 = {0.f, 0.f}, a6 = {0.f, 0.f}, a7 = {0.f, 0.f};

    #pragma unroll
    for (int i = 0; i < 16; ++i) {
        const unsigned int u = *(const unsigned int*)(vb + i * 1024);
        const float f0 = __uint_as_float(u << 16);
        const float f1 = __uint_as_float(u & 0xffff0000u);
        const float4 wa = *(const float4*)(wb + i * 16);
        const float4 wc = *(const float4*)(wb + i * 16 + 4);
        a0.x = __fmaf_rn(wa.x, f0, a0.x);  a0.y = __fmaf_rn(wa.x, f1, a0.y);
        a1.x = __fmaf_rn(wa.y, f0, a1.x);  a1.y = __fmaf_rn(wa.y, f1, a1.y);
        a2.x = __fmaf_rn(wa.z, f0, a2.x);  a2.y = __fmaf_rn(wa.z, f1, a2.y);
        a3.x = __fmaf_rn(wa.w, f0, a3.x);  a3.y = __fmaf_rn(wa.w, f1, a3.y);
        a4.x = __fmaf_rn(wc.x, f0, a4.x);  a4.y = __fmaf_rn(wc.x, f1, a4.y);
        a5.x = __fmaf_rn(wc.y, f0, a5.x);  a5.y = __fmaf_rn(wc.y, f1, a5.y);
        a6.x = __fmaf_rn(wc.z, f0, a6.x);  a6.y = __fmaf_rn(wc.z, f1, a6.y);
        a7.x = __fmaf_rn(wc.w, f0, a7.x);  a7.y = __fmaf_rn(wc.w, f1, a7.y);
    }

    const size_t orow = ((size_t)(b * E_ + 8 * ih) * C_ + c) * HW_ + blk * 64 + px;
    const size_t jstr = (size_t)C_ * HW_;
#define STORE_J(jj, areg)                                                  \
    {                                                                      \
        float2 o;                                                          \
        o.x = selu_f(areg.x);                                              \
        o.y = selu_f(areg.y);                                              \
        *(float2*)(out + orow + (size_t)(jj) * jstr) = o;                  \
    }
    STORE_J(0, a0); STORE_J(1, a1); STORE_J(2, a2); STORE_J(3, a3);
    STORE_J(4, a4); STORE_J(5, a5); STORE_J(6, a6); STORE_J(7, a7);
#undef STORE_J
}

// ---------------- kernel 3 (fallback): V conv (MFMA) + combine + selu ----------------
#define K3_CH 2
#define VCS 20
#define VIS 1284

__global__ __launch_bounds__(256, 2)
void out_kernel(const float* __restrict__ x,
                const float* __restrict__ Wv, const float* __restrict__ bv,
                const float* __restrict__ wts, float* __restrict__ out)
{
    __shared__ __align__(16) unsigned short sV[E_ * VIS];   // V staged bf16
    __shared__ __align__(16) unsigned short Wvh[64 * WPAD], Wvl[64 * WPAD];

    const int t    = threadIdx.x;
    const int b    = blockIdx.x >> 7;
    const int blk  = blockIdx.x & 127;
    const int wv   = t >> 6;
    const int lane = t & 63;
    const int quad = lane >> 4;
    const int pxl  = lane & 15;
    const int m16  = lane & 15;
    const int c    = t >> 2;     // combine: channel
    const int q    = t & 3;      // combine: j-quad

    stage_w(Wv, Wvh, Wvl, t);
    __syncthreads();

    for (int chunk = 0; chunk < K3_CH; ++chunk) {
        const int p0 = blk * (16 * K3_CH) + chunk * 16;

        short8 xh[4][2], xl[4][2];
        #pragma unroll
        for (int mi = 0; mi < 4; ++mi) {
            const int im = 4 * wv + mi;
            const float* xg = x + ((size_t)(b * E_ + im) * CIN_) * HW_ + p0 + pxl;
            #pragma unroll
            for (int kk = 0; kk < 2; ++kk) {
                float xv[8];
                #pragma unroll
                for (int j = 0; j < 8; ++j)
                    xv[j] = xg[(size_t)(kk * 32 + quad * 8 + j) * HW_];
                #pragma unroll
                for (int j = 0; j < 8; ++j) {
                    const unsigned short h = f2bf(xv[j]);
                    xh[mi][kk][j] = (short)h;
                    xl[mi][kk][j] = (short)f2bf(xv[j] - bf2f(h));
                }
            }
        }

        #pragma unroll
        for (int cb = 0; cb < 4; ++cb) {
            short8 ah[2], al[2];
            #pragma unroll
            for (int kk = 0; kk < 2; ++kk) {
                const int off = (cb * 16 + m16) * WPAD + kk * 32 + quad * 8;
                ah[kk] = *(const short8*)&Wvh[off];
                al[kk] = *(const short8*)&Wvl[off];
            }
            float bvv[4];
            #pragma unroll
            for (int r = 0; r < 4; ++r) bvv[r] = bv[cb * 16 + quad * 4 + r];
            #pragma unroll
            for (int mi = 0; mi < 4; ++mi) {
                floatx4 d = {0.f, 0.f, 0.f, 0.f};
                #pragma unroll
                for (int kk = 0; kk < 2; ++kk) {
                    d = __builtin_amdgcn_mfma_f32_16x16x32_bf16(ah[kk], xh[mi][kk], d, 0, 0, 0);
                    d = __builtin_amdgcn_mfma_f32_16x16x32_bf16(ah[kk], xl[mi][kk], d, 0, 0, 0);
                    d = __builtin_amdgcn_mfma_f32_16x16x32_bf16(al[kk], xh[mi][kk], d, 0, 0, 0);
                }
                const int im = 4 * wv + mi;
                #pragma unroll
                for (int r = 0; r < 4; ++r)
                    sV[im * VIS + (cb * 16 + quad * 4 + r) * VCS + pxl] = f2bf(d[r] + bvv[r]);
            }
        }
        __syncthreads();

        float acc2[4][16];
        #pragma unroll
        for (int jj = 0; jj < 4; ++jj)
            #pragma unroll
            for (int pp = 0; pp < 16; ++pp) acc2[jj][pp] = 0.f;

        #pragma unroll 4
        for (int i2 = 0; i2 < 16; ++i2) {
            const float4 w4 = *(const float4*)&wts[(((size_t)b * C_ + c) * E_ + i2) * E_ + 4 * q];
            const unsigned short* vp = &sV[i2 * VIS + c * VCS];
            float vvv[16];
            #pragma unroll
            for (int pq = 0; pq < 4; ++pq) {
                const uint2 u = *(const uint2*)(vp + 4 * pq);
                vvv[4 * pq + 0] = __uint_as_float(u.x << 16);
                vvv[4 * pq + 1] = __uint_as_float(u.x & 0xffff0000u);
                vvv[4 * pq + 2] = __uint_as_float(u.y << 16);
                vvv[4 * pq + 3] = __uint_as_float(u.y & 0xffff0000u);
            }
            const float wj0 = w4.x, wj1 = w4.y, wj2 = w4.z, wj3 = w4.w;
            #pragma unroll
            for (int pp = 0; pp < 16; ++pp) {
                acc2[0][pp] = __fmaf_rn(wj0, vvv[pp], acc2[0][pp]);
                acc2[1][pp] = __fmaf_rn(wj1, vvv[pp], acc2[1][pp]);
                acc2[2][pp] = __fmaf_rn(wj2, vvv[pp], acc2[2][pp]);
                acc2[3][pp] = __fmaf_rn(wj3, vvv[pp], acc2[3][pp]);
            }
        }

        #pragma unroll
        for (int jj = 0; jj < 4; ++jj) {
            const int j = 4 * q + jj;
            float* op = out + ((size_t)((b * E_ + j) * C_ + c)) * HW_ + p0;
            #pragma unroll
            for (int pq = 0; pq < 4; ++pq) {
                float4 o;
                o.x = selu_f(acc2[jj][4 * pq + 0]);
                o.y = selu_f(acc2[jj][4 * pq + 1]);
                o.z = selu_f(acc2[jj][4 * pq + 2]);
                o.w = selu_f(acc2[jj][4 * pq + 3]);
                *(float4*)(op + 4 * pq) = o;
            }
        }
        __syncthreads();
    }
}

extern "C" void kernel_launch(void* const* d_in, const int* in_sizes, int n_in,
                              void* d_out, int out_size, void* d_ws, size_t ws_size,
                              hipStream_t stream)
{
    (void)in_sizes; (void)n_in; (void)out_size;
    const float* x  = (const float*)d_in[0];
    const float* Wv = (const float*)d_in[1];
    const float* bv = (const float*)d_in[2];
    const float* Wk = (const float*)d_in[3];
    const float* bk = (const float*)d_in[4];
    const float* Wq = (const float*)d_in[5];
    const float* bq = (const float*)d_in[6];
    float* out = (float*)d_out;

    const size_t wts_b  = (size_t)B_ * C_ * E_ * E_ * sizeof(float);        // 0.5 MB
    const size_t part_b = (size_t)512 * C_ * E_ * E_ * sizeof(float);       // 33.5 MB
    const size_t v_b    = (size_t)B_ * E_ * C_ * HW_ * sizeof(unsigned short); // 67.1 MB

    float* wts = (float*)d_ws;
    float* part = nullptr;
    unsigned short* vbuf = nullptr;
    int use_atomic, have_v;

    if (ws_size >= wts_b + part_b + v_b) {
        use_atomic = 0; have_v = 1;
        part = (float*)((char*)d_ws + wts_b);
        vbuf = (unsigned short*)((char*)d_ws + wts_b + part_b);
    } else if (ws_size >= wts_b + part_b) {
        use_atomic = 0; have_v = 0;
        part = (float*)((char*)d_ws + wts_b);
    } else if (ws_size >= wts_b + v_b) {
        use_atomic = 1; have_v = 1;
        vbuf = (unsigned short*)((char*)d_ws + wts_b);
    } else {
        use_atomic = 1; have_v = 0;
    }

    if (use_atomic)
        hipMemsetAsync(d_ws, 0, wts_b, stream);

    dots_kernel<<<dim3(512), dim3(256), 0, stream>>>(x, Wk, bk, Wq, bq, Wv, bv,
                                                     vbuf, wts, part, use_atomic);
    if (!use_atomic)
        reduce_kernel<<<dim3(128), dim3(256), 0, stream>>>(part, wts);
    softmax_kernel<<<dim3(32), dim3(256), 0, stream>>>(wts);
    if (have_v)
        combine_kernel<<<dim3(8192), dim3(256), 0, stream>>>(vbuf, wts, out);
    else
        out_kernel<<<dim3(1024), dim3(256), 0, stream>>>(x, Wv, bv, wts, out);
}